// Round 9
// baseline (584.173 us; speedup 1.0000x reference)
//
#include <hip/hip_runtime.h>

// ============ DIAGNOSTIC BUILD: each kernel body runs 2x (idempotent) =======
// Purpose: double per-dispatch durations so kernels cross the 77us harness-fill
// threshold and appear in the top-5 profile rows with real names/durations.
// Output is bit-identical (atomicAdd gated to last rep).

constexpr int kB = 8;
constexpr int kN = 2046;
constexpr int kC = 2048;   // kN + 2
constexpr int kD = 128;
constexpr int kJ = 128;
constexpr int kL = 2;

typedef short bfrag8 __attribute__((ext_vector_type(8)));
typedef float f32x4 __attribute__((ext_vector_type(4)));

// ---------- bf16 helpers ----------
__device__ __forceinline__ float bf2f(unsigned short h) {
  union { unsigned u; float f; } x; x.u = ((unsigned)h) << 16; return x.f;
}
__device__ __forceinline__ unsigned short f2bf(float f) {
  union { float f; unsigned u; } x; x.f = f;
  unsigned u = x.u;
  if ((u & 0x7fffffffu) > 0x7f800000u) return (unsigned short)((u >> 16) | 0x40);
  return (unsigned short)((u + 0x7fffu + ((u >> 16) & 1u)) >> 16);
}
__device__ __forceinline__ unsigned short f2bf_fast(float f) {  // finite inputs
  union { float f; unsigned u; } x; x.f = f;
  return (unsigned short)((x.u + 0x7fffu + ((x.u >> 16) & 1u)) >> 16);
}
__device__ __forceinline__ void split2(float x, unsigned short& h, unsigned short& l) {
  unsigned short hh = f2bf_fast(x);
  h = hh;
  l = f2bf_fast(x - bf2f(hh));
}
__device__ __forceinline__ unsigned packhl(float x) {
  unsigned short h, l; split2(x, h, l);
  return (unsigned)h | ((unsigned)l << 16);
}
__device__ __forceinline__ float unpackhl(unsigned u) {
  return bf2f((unsigned short)u) + bf2f((unsigned short)(u >> 16));
}

// ---------- raw input pointers ----------
struct Raw {
  const void *ops, *mask;
  const int *rel, *bidx, *eidx;
  const void *ibw, *ibb, *iew, *ieb;
  const void *bbw, *bbb, *bew, *beb;
  const void *sw, *sb;
  const void *aw, *ab;
  const void *scw, *scb;
  const void *aow, *aob;
  const void *mw, *mb;
};

__device__ __forceinline__ float rp(const void* p, size_t i, bool bf) {
  return bf ? bf2f(((const unsigned short*)p)[i]) : ((const float*)p)[i];
}

__device__ __forceinline__ bool sniff(const Raw& r) {
  const unsigned* x = (const unsigned*)r.ops;
  int lane = (int)(threadIdx.x & 63);
  int hits = 0;
  #pragma unroll
  for (int q = 0; q < 16; ++q) {
    unsigned w = x[q * 64 + lane];
    unsigned e0 = (w >> 7) & 0xFFu;
    hits += (e0 == 0u || (e0 >= 96u && e0 <= 134u)) ? 1 : 0;
  }
  #pragma unroll
  for (int o = 1; o < 64; o <<= 1) hits += __shfl_xor(hits, o);
  return hits >= 512;
}

// ---------- workspace layout (float offsets) ----------
constexpr size_t OF_FEATS = 0;
constexpr size_t OF_SEQ   = 2097152;
constexpr size_t OF_ATTN  = 4194304;
constexpr size_t OF_V     = 6291456;
constexpr size_t OF_SQ    = 8388608;
constexpr size_t OF_SK    = 8404992;
constexpr size_t OF_U     = 8421376;
constexpr size_t OF_PART  = 8422400;
constexpr size_t OF_BMIX  = 8423424;
constexpr size_t OF_WT    = 8423680;

constexpr int WT_SEQH = 0;
constexpr int WT_SEQL = 49152;
constexpr int WT_VH   = 98304;
constexpr int WT_VL   = 114688;
constexpr int WT_MIXH = 131072;
constexpr int WT_MIXL = 163840;
constexpr int WT_LS   = 196608;

constexpr int RP_WT   = 640;
constexpr int RP_WF   = RP_WT + 258;
constexpr int RP_UV   = RP_WF + 2;
constexpr int RP_BE   = RP_UV + 16;
constexpr int RP_PART = RP_BE + 1;
constexpr int RP_CAST = RP_PART + 1023;
constexpr int RP_TOT  = RP_CAST + 4092;

__device__ __forceinline__ f32x4 mfma16(bfrag8 a, bfrag8 b, f32x4 c) {
  return __builtin_amdgcn_mfma_f32_16x16x32_bf16(a, b, c, 0, 0, 0);
}

// ---------- K0: mega-prep (R7/R8 form, body x2) ----------
__global__ __launch_bounds__(256) void k_prep(Raw r, unsigned* __restrict__ feats,
                                              unsigned* __restrict__ bits32,
                                              unsigned short* __restrict__ wt,
                                              float* __restrict__ bmix,
                                              float* __restrict__ u2,
                                              float* __restrict__ part) {
  __shared__ __align__(16) char smem[34816];
  int bid = blockIdx.x, t = threadIdx.x;
  bool bf = sniff(r);

  #pragma unroll 1
  for (int rep_ = 0; rep_ < 2; ++rep_) {
  if (bid < RP_WT) {
    int idx = bid * 256 + t;
    int l = idx / 81920;
    int rr = idx - l * 81920;
    const void* src; size_t si; int dH, dL, k, n;
    if (rr < 49152) {
      k = rr >> 7; n = rr & 127;
      src = r.sw; si = (size_t)l * 49152 + (size_t)k * 128 + n;
      dH = l * WT_LS + WT_SEQH; dL = l * WT_LS + WT_SEQL;
    } else if (rr < 65536) {
      int e = rr - 49152; k = e >> 7; n = e & 127;
      src = r.aw; si = (size_t)l * 49152 + (size_t)k * 384 + 256 + n;
      dH = l * WT_LS + WT_VH; dL = l * WT_LS + WT_VL;
    } else {
      int e = rr - 65536; k = e >> 7; n = e & 127;
      src = r.mw; si = (size_t)l * 32768 + (size_t)k * 128 + n;
      dH = l * WT_LS + WT_MIXH; dL = l * WT_LS + WT_MIXL;
    }
    float v = rp(src, si, bf);
    unsigned short h, lo;
    split2(v, h, lo);
    int kc = k >> 5, q = (k >> 3) & 3, e8 = k & 7;
    int fa = ((kc * 8 + (n >> 4)) * 64 + (q * 16 + (n & 15))) * 8 + e8;
    wt[dH + fa] = h;
    wt[dL + fa] = lo;
  } else if (bid < RP_WF) {
    int rb = bid - RP_WT;
    int l = rb / 129, d1 = rb - l * 129;
    float* vsh = (float*)smem;
    size_t mixbot = (size_t)l * 32768 + 16384;
    if (t < 128) {
      vsh[t] = (d1 < 128) ? rp(r.aow, (size_t)l * 16384 + (size_t)d1 * 128 + t, bf)
                          : rp(r.aob, (size_t)l * 128 + t, bf);
    }
    __syncthreads();
    if (t < 128) {
      int d = t;
      float acc = 0.f;
      if (bf) {
        const unsigned short* mwp = (const unsigned short*)r.mw + mixbot + d;
        #pragma unroll 8
        for (int d2 = 0; d2 < kD; ++d2) acc += vsh[d2] * bf2f(mwp[(size_t)d2 * 128]);
      } else {
        const float* mwp = (const float*)r.mw + mixbot + d;
        #pragma unroll 8
        for (int d2 = 0; d2 < kD; ++d2) acc += vsh[d2] * mwp[(size_t)d2 * 128];
      }
      if (d1 < 128) {
        unsigned short h, lo;
        split2(acc, h, lo);
        int k = 128 + d1;
        int kc = k >> 5, q = (k >> 3) & 3, e8 = k & 7;
        int fa = ((kc * 8 + (d >> 4)) * 64 + (q * 16 + (d & 15))) * 8 + e8;
        wt[l * WT_LS + WT_MIXH + fa] = h;
        wt[l * WT_LS + WT_MIXL + fa] = lo;
      } else {
        bmix[(size_t)l * kD + d] = acc + rp(r.mb, (size_t)l * 128 + d, bf);
      }
    }
  } else if (bid < RP_UV) {
    int l = bid - RP_WF;
    float* swm = (float*)smem;
    float* red = (float*)smem + 256;
    if (t < 128) {
      swm[t]       = rp(r.scw, (size_t)l * 256 + t, bf);
      swm[128 + t] = rp(r.scw, (size_t)l * 256 + 128 + t, bf);
    }
    __syncthreads();
    if (t < 128) {
      int k = t;
      size_t base = (size_t)l * 49152 + (size_t)k * 384;
      float uq = 0.f, uk = 0.f;
      if (bf) {
        const unsigned* aq = (const unsigned*)((const unsigned short*)r.aw + base);
        #pragma unroll 8
        for (int g = 0; g < 64; ++g) {
          unsigned wq = aq[g];
          uq += bf2f((unsigned short)(wq & 0xffffu)) * swm[2 * g]
              + bf2f((unsigned short)(wq >> 16))     * swm[2 * g + 1];
        }
        #pragma unroll 8
        for (int g = 0; g < 64; ++g) {
          unsigned wk = aq[64 + g];
          uk += bf2f((unsigned short)(wk & 0xffffu)) * swm[128 + 2 * g]
              + bf2f((unsigned short)(wk >> 16))     * swm[128 + 2 * g + 1];
        }
      } else {
        const float* aq = (const float*)r.aw + base;
        #pragma unroll 8
        for (int g = 0; g < 32; ++g) {
          float4 v = *(const float4*)(aq + g * 4);
          uq += v.x * swm[4 * g] + v.y * swm[4 * g + 1]
              + v.z * swm[4 * g + 2] + v.w * swm[4 * g + 3];
        }
        #pragma unroll 8
        for (int g = 0; g < 32; ++g) {
          float4 v = *(const float4*)(aq + 128 + g * 4);
          uk += v.x * swm[128 + 4 * g] + v.y * swm[128 + 4 * g + 1]
              + v.z * swm[128 + 4 * g + 2] + v.w * swm[128 + 4 * g + 3];
        }
      }
      float* u = u2 + (size_t)l * 272;
      u[k] = uq; u[128 + k] = uk;
      red[k] = rp(r.ab, (size_t)l * 384 + k, bf) * swm[k]
             + rp(r.ab, (size_t)l * 384 + 128 + k, bf) * swm[128 + k];
    }
    __syncthreads();
    if (t == 0) {
      float s = rp(r.scb, l, bf);
      for (int i = 0; i < 128; ++i) s += red[i];
      u2[(size_t)l * 272 + 256] = s;
    }
  } else if (bid < RP_BE) {
    int rb = bid - RP_UV;
    int b = rb >> 1, sel = rb & 1;
    float* msh = (float*)smem;
    const int* idx = (sel ? r.eidx : r.bidx) + b * kJ;
    const void* wv = sel ? r.iew : r.ibw;
    const void* bb = sel ? r.ieb : r.ibb;
    if (t < 128) {
      int d = t;
      float acc = 0.f;
      if (bf) {
        const unsigned short* op = (const unsigned short*)r.ops;
        #pragma unroll 4
        for (int j = 0; j < kJ; ++j)
          acc += bf2f(op[((size_t)b * kN + idx[j]) * kD + d]);
      } else {
        const float* op = (const float*)r.ops;
        #pragma unroll 4
        for (int j = 0; j < kJ; ++j)
          acc += op[((size_t)b * kN + idx[j]) * kD + d];
      }
      msh[d] = acc * (1.0f / kJ);
    }
    __syncthreads();
    if (t < 128) {
      int d = t;
      float o;
      if (bf) {
        const unsigned short* wp = (const unsigned short*)wv + d;
        o = bf2f(((const unsigned short*)bb)[d]);
        #pragma unroll 8
        for (int k2 = 0; k2 < kD; ++k2) o += msh[k2] * bf2f(wp[(size_t)k2 * kD]);
      } else {
        const float* wp = (const float*)wv + d;
        o = ((const float*)bb)[d];
        #pragma unroll 8
        for (int k2 = 0; k2 < kD; ++k2) o += msh[k2] * wp[(size_t)k2 * kD];
      }
      feats[(size_t)b * kC * kD + (size_t)(kN + sel) * kD + d] = packhl(o);
    }
  } else if (bid < RP_PART) {
    #pragma unroll
    for (int q = 0; q < 4; ++q) part[q * 256 + t] = 0.f;
  } else if (bid < RP_CAST) {
    int idx = (bid - RP_PART) * 256 + t;
    size_t elem = (size_t)idx * 8;
    int b = (int)(elem / (size_t)(kN * kD));
    int rr = (int)(elem - (size_t)b * (kN * kD));
    unsigned* dst = feats + (size_t)b * kC * kD + rr;
    uint4 o0, o1;
    if (bf) {
      uint4 in = ((const uint4*)r.ops)[idx];
      o0.x = in.x & 0xffffu; o0.y = in.x >> 16;
      o0.z = in.y & 0xffffu; o0.w = in.y >> 16;
      o1.x = in.z & 0xffffu; o1.y = in.z >> 16;
      o1.z = in.w & 0xffffu; o1.w = in.w >> 16;
    } else {
      float4 a = ((const float4*)r.ops)[idx * 2];
      float4 c = ((const float4*)r.ops)[idx * 2 + 1];
      o0.x = packhl(a.x); o0.y = packhl(a.y); o0.z = packhl(a.z); o0.w = packhl(a.w);
      o1.x = packhl(c.x); o1.y = packhl(c.y); o1.z = packhl(c.z); o1.w = packhl(c.w);
    }
    *(uint4*)dst = o0;
    *(uint4*)(dst + 4) = o1;
  } else {
    int wave = t >> 6, lane = t & 63;
    int rr = (bid - RP_CAST) * 4 + wave;
    int b = rr / kN, i = rr - b * kN;
    unsigned* rowbuf = (unsigned*)smem + wave * 2176;
    unsigned word = 0;
    if (bf) {
      const unsigned* g = (const unsigned*)((const char*)r.mask + (size_t)rr * (kN * 2));
      #pragma unroll
      for (int q = 0; q < 16; ++q) {
        int a = q * 64 + lane;
        unsigned v = (a < 1023) ? g[a] : 0u;
        rowbuf[a + (a >> 4)] = v;
      }
      #pragma unroll
      for (int q = 0; q < 16; ++q) {
        int a = lane * 16 + q;
        unsigned v = rowbuf[a + (a >> 4)];
        unsigned b0 = ((v & 0xffffu) != 0u) ? 1u : 0u;
        unsigned b1 = ((v >> 16)     != 0u) ? 1u : 0u;
        word |= (b0 << (2 * q)) | (b1 << (2 * q + 1));
      }
    } else {
      const unsigned* g = (const unsigned*)((const char*)r.mask + (size_t)rr * (kN * 4));
      #pragma unroll
      for (int q = 0; q < 32; ++q) {
        int a = q * 64 + lane;
        unsigned v = (a < 2046) ? g[a] : 0u;
        rowbuf[a + (a >> 4)] = v;
      }
      #pragma unroll
      for (int q = 0; q < 32; ++q) {
        int a = lane * 32 + q;
        unsigned v = rowbuf[a + (a >> 4)];
        union { unsigned u; float f; } x; x.u = v;
        if (x.f != 0.f) word |= (1u << q);
      }
    }
    bits32[((size_t)b * kC + i) * 64 + lane] = word;
  }
  __syncthreads();
  }  // rep_
}

// ---------- K1: stage1 (R8 form, body x2) ----------
__global__ __launch_bounds__(256) void k_stage1(Raw r, int l,
    const unsigned* __restrict__ feats, const unsigned short* __restrict__ wt,
    const float* __restrict__ u2, unsigned* __restrict__ seq,
    unsigned short* __restrict__ Vt, float* __restrict__ sq, float* __restrict__ sk)
{
  __shared__ __align__(16) char smem[19712];
  unsigned short (*Ah)[32 * 72] = (unsigned short(*)[32 * 72])smem;
  unsigned short (*Al)[32 * 72] = (unsigned short(*)[32 * 72])(smem + 9216);
  float* su = (float*)(smem + 18432);
  int bid = blockIdx.x, t = threadIdx.x;
  int lane = t & 63, w = t >> 6, m = lane & 15, quad = lane >> 4;
  bool bf = sniff(r);
  const unsigned short* wl = wt + (size_t)l * WT_LS;

  #pragma unroll 1
  for (int rep_ = 0; rep_ < 2; ++rep_) {
  if (bid >= 16) {
    int g = bid - 16;
    bool isv = g >= 512;
    int rb = isv ? g - 512 : g;
    int gr0 = rb * 32;
    int b = gr0 >> 11, r0 = gr0 & 2047;
    int arow = t >> 3, kq = (t & 7) * 8;
    int nl = r0 + arow;
    const unsigned* fb = feats + (size_t)b * kC * kD;
    const unsigned *s0, *s1, *s2;
    if (!isv) {
      int nr = (nl <= kN - 1) ? nl : (kN - 1);
      const int* rel = r.rel + ((size_t)b * kN + nr) * 2;
      int rpd = rel[0], rsc = rel[1];
      int p = (rpd < 0) ? kN : rpd;
      int s = (rsc < 0) ? (kN + 1) : rsc;
      s0 = fb + (size_t)nl * kD;
      s1 = fb + (size_t)p * kD;
      s2 = fb + (size_t)s * kD;
    } else {
      s0 = fb + (size_t)nl * kD; s1 = s0; s2 = s0;
      su[t] = u2[(size_t)l * 272 + t];
    }
    const int K = isv ? 128 : 384;
    const unsigned short* wth = isv ? (wl + WT_VH) : (wl + WT_SEQH);
    const unsigned short* wtl = isv ? (wl + WT_VL) : (wl + WT_SEQL);
    const unsigned short* pbh = wth + (size_t)(w * 2) * 512 + lane * 8;
    const unsigned short* pbl = wtl + (size_t)(w * 2) * 512 + lane * 8;
    float pq = 0.f, pk2 = 0.f;

    auto build = [&](int kb, int buf) {
      int kg = kb + kq;
      const unsigned* sp;
      if (!isv) sp = (kg < 128) ? (s0 + kg) : (kg < 256) ? (s1 + kg - 128) : (s2 + kg - 256);
      else      sp = s0 + kg;
      uint4 U0 = *(const uint4*)sp;
      uint4 U1 = *(const uint4*)(sp + 4);
      if (isv) {
        float f0 = unpackhl(U0.x), f1 = unpackhl(U0.y), f2 = unpackhl(U0.z), f3 = unpackhl(U0.w);
        float f4 = unpackhl(U1.x), f5 = unpackhl(U1.y), f6 = unpackhl(U1.z), f7 = unpackhl(U1.w);
        pq  += f0 * su[kg]     + f1 * su[kg + 1] + f2 * su[kg + 2] + f3 * su[kg + 3]
             + f4 * su[kg + 4] + f5 * su[kg + 5] + f6 * su[kg + 6] + f7 * su[kg + 7];
        pk2 += f0 * su[128 + kg]     + f1 * su[128 + kg + 1] + f2 * su[128 + kg + 2] + f3 * su[128 + kg + 3]
             + f4 * su[128 + kg + 4] + f5 * su[128 + kg + 5] + f6 * su[128 + kg + 6] + f7 * su[128 + kg + 7];
      }
      uint4 ph, pl;
      ph.x = (U0.x & 0xffffu) | (U0.y << 16);
      pl.x = (U0.x >> 16)     | (U0.y & 0xffff0000u);
      ph.y = (U0.z & 0xffffu) | (U0.w << 16);
      pl.y = (U0.z >> 16)     | (U0.w & 0xffff0000u);
      ph.z = (U1.x & 0xffffu) | (U1.y << 16);
      pl.z = (U1.x >> 16)     | (U1.y & 0xffff0000u);
      ph.w = (U1.z & 0xffffu) | (U1.w << 16);
      pl.w = (U1.z >> 16)     | (U1.w & 0xffff0000u);
      *(uint4*)&Ah[buf][arow * 72 + kq] = ph;
      *(uint4*)&Al[buf][arow * 72 + kq] = pl;
    };

    f32x4 acc[2][2];
    #pragma unroll
    for (int mi = 0; mi < 2; ++mi) { acc[mi][0] = {0.f,0.f,0.f,0.f}; acc[mi][1] = {0.f,0.f,0.f,0.f}; }

    __syncthreads();
    build(0, 0);
    __syncthreads();
    for (int kb = 0; kb < K; kb += 64) {
      int cur = (kb >> 6) & 1;
      if (kb + 64 < K) build(kb + 64, cur ^ 1);
      #pragma unroll
      for (int kk = 0; kk < 2; ++kk) {
        int kc = (kb >> 5) + kk;
        bfrag8 bh0 = *(const bfrag8*)(pbh + (size_t)kc * 4096);
        bfrag8 bh1 = *(const bfrag8*)(pbh + (size_t)kc * 4096 + 512);
        bfrag8 bl0 = {}, bl1 = {};
        if (!bf) {
          bl0 = *(const bfrag8*)(pbl + (size_t)kc * 4096);
          bl1 = *(const bfrag8*)(pbl + (size_t)kc * 4096 + 512);
        }
        #pragma unroll
        for (int mi = 0; mi < 2; ++mi) {
          bfrag8 ah = *(const bfrag8*)&Ah[cur][(mi * 16 + m) * 72 + kk * 32 + quad * 8];
          bfrag8 al = *(const bfrag8*)&Al[cur][(mi * 16 + m) * 72 + kk * 32 + quad * 8];
          acc[mi][0] = mfma16(ah, bh0, acc[mi][0]);
          acc[mi][0] = mfma16(al, bh0, acc[mi][0]);
          acc[mi][1] = mfma16(ah, bh1, acc[mi][1]);
          acc[mi][1] = mfma16(al, bh1, acc[mi][1]);
          if (!bf) {
            acc[mi][0] = mfma16(ah, bl0, acc[mi][0]);
            acc[mi][1] = mfma16(ah, bl1, acc[mi][1]);
          }
        }
      }
      __syncthreads();
    }

    int n0 = w * 32 + m;
    if (!isv) {
      float bv0 = rp(r.sb, (size_t)l * 128 + n0, bf);
      float bv1 = rp(r.sb, (size_t)l * 128 + n0 + 16, bf);
      #pragma unroll
      for (int mi = 0; mi < 2; ++mi)
        #pragma unroll
        for (int reg = 0; reg < 4; ++reg) {
          int ra = r0 + mi * 16 + quad * 4 + reg;
          if (ra < kN) {
            seq[((size_t)b * kC + ra) * kD + n0]      = packhl(acc[mi][0][reg] + bv0);
            seq[((size_t)b * kC + ra) * kD + n0 + 16] = packhl(acc[mi][1][reg] + bv1);
          }
        }
    } else {
      float bv0 = rp(r.ab, (size_t)l * 384 + 256 + n0, bf);
      float bv1 = rp(r.ab, (size_t)l * 384 + 256 + n0 + 16, bf);
      unsigned short* vtb = Vt + (size_t)b * 262144;
      #pragma unroll
      for (int mi = 0; mi < 2; ++mi)
        #pragma unroll
        for (int reg = 0; reg < 4; ++reg) {
          int c = r0 + mi * 16 + quad * 4 + reg;
          int kc = c >> 5, cq = (c >> 3) & 3, e8 = c & 7;
          int lp = cq * 16 + m;
          vtb[((kc * 8 + w * 2) * 64 + lp) * 8 + e8]       = f2bf_fast(acc[mi][0][reg] + bv0);
          vtb[((kc * 8 + w * 2 + 1) * 64 + lp) * 8 + e8]   = f2bf_fast(acc[mi][1][reg] + bv1);
        }
      pq  += __shfl_xor(pq, 1);  pq  += __shfl_xor(pq, 2);  pq  += __shfl_xor(pq, 4);
      pk2 += __shfl_xor(pk2, 1); pk2 += __shfl_xor(pk2, 2); pk2 += __shfl_xor(pk2, 4);
      if ((t & 7) == 0) {
        sq[(size_t)b * kC + nl] = pq + u2[(size_t)l * 272 + 256];
        sk[(size_t)b * kC + nl] = pk2;
      }
    }
  } else {
    int rb = bid;
    int b = rb >> 1, sel = rb & 1;
    float* msh = (float*)smem;
    const int* idx = (sel ? r.eidx : r.bidx) + b * kJ;
    const void* wv = sel ? r.bew : r.bbw;
    const void* bb = sel ? r.beb : r.bbb;
    size_t wbase = (size_t)l * kD * kD, bbase = (size_t)l * kD;
    if (t < 128) {
      int d = t;
      const unsigned* fb2 = feats + (size_t)b * kC * kD;
      float acc = 0.f;
      #pragma unroll 4
      for (int j = 0; j < kJ; ++j) acc += unpackhl(fb2[(size_t)idx[j] * kD + d]);
      msh[d] = acc * (1.0f / kJ);
    }
    __syncthreads();
    if (t < 128) {
      int d = t;
      float o;
      if (bf) {
        const unsigned short* wp = (const unsigned short*)wv + wbase + d;
        o = bf2f(((const unsigned short*)bb)[bbase + d]);
        #pragma unroll 8
        for (int k2 = 0; k2 < kD; ++k2) o += msh[k2] * bf2f(wp[(size_t)k2 * kD]);
      } else {
        const float* wp = (const float*)wv + wbase + d;
        o = ((const float*)bb)[bbase + d];
        #pragma unroll 8
        for (int k2 = 0; k2 < kD; ++k2) o += msh[k2] * wp[(size_t)k2 * kD];
      }
      seq[(size_t)b * kC * kD + (size_t)(kN + sel) * kD + d] = packhl(o);
    }
  }
  __syncthreads();
  }  // rep_
}

// ---------- K2: MFMA PV (R8 form, body x2) ----------
__global__ __launch_bounds__(256) void k_attn_pv_mfma(
    const unsigned* __restrict__ bits,
    const float* __restrict__ sq, const float* __restrict__ sk,
    const unsigned short* __restrict__ Vt,
    unsigned* __restrict__ outw)
{
  int b = blockIdx.y;
  int i0 = blockIdx.x * 32;
  int t = threadIdx.x, lane = t & 63, w = t >> 6;

  __shared__ unsigned short pshare[2][1024];
  __shared__ float sklds[kC];
  __shared__ unsigned bitlds[2048];
  __shared__ float ssq[32], smx[32], szv[32];

  #pragma unroll 1
  for (int rep_ = 0; rep_ < 2; ++rep_) {
  const float* skb = sk + (size_t)b * kC;
  #pragma unroll
  for (int q = 0; q < 8; ++q) sklds[q * 256 + t] = skb[q * 256 + t];
  const unsigned* bitrow = bits + ((size_t)b * kC + i0) * 64;
  #pragma unroll
  for (int q = 0; q < 8; ++q) bitlds[q * 256 + t] = bitrow[q * 256 + t];
  if (t < 32) ssq[t] = sq[(size_t)b * kC + i0 + t];
  __syncthreads();

  {
    int rr = t >> 3, seg = t & 7;
    int ig = i0 + rr;
    bool ok = (ig < kN);
    float sqi2 = ssq[rr];
    const unsigned* bw = bitlds + rr * 64 + seg * 8;
    const float* sks = sklds + seg * 256;
    float mx;
    if (ok) {
      float msk = -3e38f;
      #pragma unroll 1
      for (int w8 = 0; w8 < 8; ++w8) {
        unsigned bb = bw[w8];
        #pragma unroll
        for (int q4 = 0; q4 < 8; ++q4) {
          float4 skv = *(const float4*)(sks + w8 * 32 + q4 * 4);
          unsigned nib = bb >> (q4 * 4);
          msk = (nib & 1u) ? fmaxf(msk, skv.x) : msk;
          msk = (nib & 2u) ? fmaxf(msk, skv.y) : msk;
          msk = (nib & 4u) ? fmaxf(msk, skv.z) : msk;
          msk = (nib & 8u) ? fmaxf(msk, skv.w) : msk;
        }
      }
      #pragma unroll
      for (int d2 = 1; d2 < 8; d2 <<= 1) msk = fmaxf(msk, __shfl_xor(msk, d2));
      float s = sqi2 + msk;
      mx = fmaxf(0.f, fmaxf(s, 0.01f * s));
    } else {
      float s = sqi2 + sklds[ig & (kC - 1)];
      mx = fmaxf(0.f, fmaxf(s, 0.01f * s));
    }
    float emx = __expf(-mx);
    float zs = 0.f;
    if (ok) {
      #pragma unroll 1
      for (int w8 = 0; w8 < 8; ++w8) {
        unsigned bb = bw[w8];
        #pragma unroll
        for (int q4 = 0; q4 < 8; ++q4) {
          float4 skv = *(const float4*)(sks + w8 * 32 + q4 * 4);
          unsigned nib = bb >> (q4 * 4);
          float s1 = sqi2 + skv.x, l1 = fmaxf(s1, 0.01f * s1);
          float s2 = sqi2 + skv.y, l2 = fmaxf(s2, 0.01f * s2);
          float s3 = sqi2 + skv.z, l3 = fmaxf(s3, 0.01f * s3);
          float s4 = sqi2 + skv.w, l4 = fmaxf(s4, 0.01f * s4);
          zs += (nib & 1u) ? __expf(l1 - mx) : emx;
          zs += (nib & 2u) ? __expf(l2 - mx) : emx;
          zs += (nib & 4u) ? __expf(l3 - mx) : emx;
          zs += (nib & 8u) ? __expf(l4 - mx) : emx;
        }
      }
    } else {
      zs = 256.f * emx;
      if ((ig >> 8) == seg) {
        float s = sqi2 + sklds[ig & (kC - 1)];
        float lr = fmaxf(s, 0.01f * s);
        zs += __expf(lr - mx) - emx;
      }
    }
    #pragma unroll
    for (int d2 = 1; d2 < 8; d2 <<= 1) zs += __shfl_xor(zs, d2);
    if (seg == 0) { smx[rr] = mx; szv[rr] = 1.0f / zs; }
  }
  __syncthreads();

  int f = t >> 1, h = t & 1;
  int mt_b = f >> 6;
  int lb = f & 63;
  int irow_l = mt_b * 16 + (lb & 15);
  int quad_b = lb >> 4;
  int i_g = i0 + irow_l;
  float sqi = ssq[irow_l];
  float mri = smx[irow_l];
  int joff = quad_b * 8 + h * 4;
  bool irow_ok = (i_g < kN);
  const unsigned char* bitb = (const unsigned char*)bitlds + irow_l * 256;

  auto buildP = [&](int k0, int buf) {
    float4 skv = *(const float4*)(sklds + k0 + joff);
    unsigned byte;
    if (irow_ok) {
      byte = bitb[(k0 >> 3) + quad_b];
    } else {
      int d0 = i_g - (k0 + quad_b * 8);
      byte = ((unsigned)d0 < 8u) ? (1u << d0) : 0u;
    }
    unsigned nib = byte >> (h * 4);
    unsigned short us[4];
    float sv[4] = {skv.x, skv.y, skv.z, skv.w};
    #pragma unroll
    for (int dj = 0; dj < 4; ++dj) {
      float s = sqi + sv[dj];
      float lr = fmaxf(s, 0.01f * s);
      float val = ((nib >> dj) & 1u) ? lr : 0.f;
      us[dj] = f2bf_fast(__expf(val - mri));
    }
    uint2 pk;
    pk.x = us[0] | ((unsigned)us[1] << 16);
    pk.y = us[2] | ((unsigned)us[3] << 16);
    *(uint2*)(&pshare[buf][f * 8 + h * 4]) = pk;
  };

  f32x4 acc00 = {0.f, 0.f, 0.f, 0.f}, acc01 = acc00, acc10 = acc00, acc11 = acc00;
  int m = lane & 15, quad = lane >> 4;
  int nbase = w * 32;
  const unsigned short* vtb = Vt + (size_t)b * 262144;
  const unsigned short* p0 = vtb + (size_t)(w * 2) * 512 + lane * 8;
  const unsigned short* p1 = p0 + 512;

  buildP(0, 0);
  bfrag8 b0n = *(const bfrag8*)p0;
  bfrag8 b1n = *(const bfrag8*)p1;
  __syncthreads();

  for (int k0 = 0; k0 < kC; k0 += 32) {
    int cur = (k0 >> 5) & 1;
    bfrag8 bf0 = b0n, bf1 = b1n;
    if (k0 + 32 < kC) {
      size_t off = (size_t)((k0 >> 5) + 1) * 4096;
      b0n = *(const bfrag8*)(p0 + off);
      b1n = *(const bfrag8*)(p1 + off);
    }
    bfrag8 a0 = *(const bfrag8*)(&pshare[cur][(0 * 64 + lane) * 8]);
    bfrag8 a1 = *(const bfrag8*)(&pshare[cur][(1 * 64 + lane) * 8]);
    acc00 = mfma16(a0, bf0, acc00);
    acc01 = mfma16(a0, bf1, acc01);
    acc10 = mfma16(a1, bf0, acc10);
    acc11 = mfma16(a1, bf1, acc11);
    if (k0 + 32 < kC) buildP(k0 + 32, cur ^ 1);
    __syncthreads();
  }

  #pragma unroll
  for (int reg = 0; reg < 4; ++reg) {
    int il_a = quad * 4 + reg;
    int i_a = i0 + il_a;
    int i_b = i_a + 16;
    float za = szv[il_a];
    float zb = szv[il_a + 16];
    unsigned* oa = outw + ((size_t)b * kC + i_a) * kD + nbase + m;
    unsigned* ob = outw + ((size_t)b * kC + i_b) * kD + nbase + m;
    oa[0]  = packhl(acc00[reg] * za);
    oa[16] = packhl(acc01[reg] * za);
    ob[0]  = packhl(acc10[reg] * zb);
    ob[16] = packhl(acc11[reg] * zb);
  }
  __syncthreads();
  }  // rep_
}

// ---------- K3: mix GEMM (R8 form, body x2; atomics on last rep only) ----------
__global__ __launch_bounds__(256) void k_mix64(Raw r, int l,
    const unsigned* __restrict__ seqb, const unsigned* __restrict__ attnw,
    const unsigned short* __restrict__ wt, const float* __restrict__ bmix,
    unsigned* __restrict__ featsOut, void* __restrict__ outx, float* __restrict__ part,
    int mode)
{
  __shared__ __align__(16) char smem[18432];
  unsigned short (*Ah)[32 * 72] = (unsigned short(*)[32 * 72])smem;
  unsigned short (*Al)[32 * 72] = (unsigned short(*)[32 * 72])(smem + 9216);
  constexpr int K = 256;
  int bid = blockIdx.x, t = threadIdx.x;
  int lane = t & 63, w = t >> 6, m = lane & 15, quad = lane >> 4;
  bool bf = sniff(r);
  int gr0 = bid * 32;
  int b = gr0 >> 11;
  int arow = t >> 3, kq = (t & 7) * 8;
  const unsigned* s0 = seqb  + (size_t)(gr0 + arow) * kD;
  const unsigned* s1 = attnw + (size_t)(gr0 + arow) * kD;
  const unsigned short* wth = wt + (size_t)l * WT_LS + WT_MIXH;
  const unsigned short* wtl = wt + (size_t)l * WT_LS + WT_MIXL;
  const unsigned short* pbh = wth + (size_t)(w * 2) * 512 + lane * 8;
  const unsigned short* pbl = wtl + (size_t)(w * 2) * 512 + lane * 8;

  #pragma unroll 1
  for (int rep_ = 0; rep_ < 2; ++rep_) {
  auto build = [&](int kb, int buf) {
    int kg = kb + kq;
    const unsigned* sp = (kg < kD) ? (s0 + kg) : (s1 + kg - kD);
    uint4 U0 = *(const uint4*)sp;
    uint4 U1 = *(const uint4*)(sp + 4);
    uint4 ph, pl;
    ph.x = (U0.x & 0xffffu) | (U0.y << 16);
    pl.x = (U0.x >> 16)     | (U0.y & 0xffff0000u);
    ph.y = (U0.z & 0xffffu) | (U0.w << 16);
    pl.y = (U0.z >> 16)     | (U0.w & 0xffff0000u);
    ph.z = (U1.x & 0xffffu) | (U1.y << 16);
    pl.z = (U1.x >> 16)     | (U1.y & 0xffff0000u);
    ph.w = (U1.z & 0xffffu) | (U1.w << 16);
    pl.w = (U1.z >> 16)     | (U1.w & 0xffff0000u);
    *(uint4*)&Ah[buf][arow * 72 + kq] = ph;
    *(uint4*)&Al[buf][arow * 72 + kq] = pl;
  };

  f32x4 acc[2][2];
  #pragma unroll
  for (int mi = 0; mi < 2; ++mi) { acc[mi][0] = {0.f,0.f,0.f,0.f}; acc[mi][1] = {0.f,0.f,0.f,0.f}; }

  build(0, 0);
  __syncthreads();
  for (int kb = 0; kb < K; kb += 64) {
    int cur = (kb >> 6) & 1;
    if (kb + 64 < K) build(kb + 64, cur ^ 1);
    #pragma unroll
    for (int kk = 0; kk < 2; ++kk) {
      int kc = (kb >> 5) + kk;
      bfrag8 bh0 = *(const bfrag8*)(pbh + (size_t)kc * 4096);
      bfrag8 bh1 = *(const bfrag8*)(pbh + (size_t)kc * 4096 + 512);
      bfrag8 bl0 = {}, bl1 = {};
      if (!bf) {
        bl0 = *(const bfrag8*)(pbl + (size_t)kc * 4096);
        bl1 = *(const bfrag8*)(pbl + (size_t)kc * 4096 + 512);
      }
      #pragma unroll
      for (int mi = 0; mi < 2; ++mi) {
        bfrag8 ah = *(const bfrag8*)&Ah[cur][(mi * 16 + m) * 72 + kk * 32 + quad * 8];
        bfrag8 al = *(const bfrag8*)&Al[cur][(mi * 16 + m) * 72 + kk * 32 + quad * 8];
        acc[mi][0] = mfma16(ah, bh0, acc[mi][0]);
        acc[mi][0] = mfma16(al, bh0, acc[mi][0]);
        acc[mi][1] = mfma16(ah, bh1, acc[mi][1]);
        acc[mi][1] = mfma16(al, bh1, acc[mi][1]);
        if (!bf) {
          acc[mi][0] = mfma16(ah, bl0, acc[mi][0]);
          acc[mi][1] = mfma16(ah, bl1, acc[mi][1]);
        }
      }
    }
    __syncthreads();
  }

  int n0 = w * 32 + m;
  float bv0 = bmix[(size_t)l * kD + n0];
  float bv1 = bmix[(size_t)l * kD + n0 + 16];
  if (mode == 0) {
    #pragma unroll
    for (int mi = 0; mi < 2; ++mi)
      #pragma unroll
      for (int reg = 0; reg < 4; ++reg) {
        size_t row = (size_t)gr0 + mi * 16 + quad * 4 + reg;
        featsOut[row * kD + n0]      = packhl(acc[mi][0][reg] + bv0);
        featsOut[row * kD + n0 + 16] = packhl(acc[mi][1][reg] + bv1);
      }
  } else {
    float sum0 = 0.f, sum1 = 0.f;
    #pragma unroll
    for (int mi = 0; mi < 2; ++mi)
      #pragma unroll
      for (int reg = 0; reg < 4; ++reg) {
        size_t row = (size_t)gr0 + mi * 16 + quad * 4 + reg;
        float v0 = acc[mi][0][reg] + bv0;
        float v1 = acc[mi][1][reg] + bv1;
        if (bf) {
          unsigned short* o = (unsigned short*)outx + 1024;
          o[row * kD + n0]      = f2bf(v0);
          o[row * kD + n0 + 16] = f2bf(v1);
        } else {
          float* o = (float*)outx + 1024;
          o[row * kD + n0]      = v0;
          o[row * kD + n0 + 16] = v1;
        }
        sum0 += v0; sum1 += v1;
      }
    sum0 += __shfl_xor(sum0, 16); sum0 += __shfl_xor(sum0, 32);
    sum1 += __shfl_xor(sum1, 16); sum1 += __shfl_xor(sum1, 32);
    if (quad == 0 && rep_ == 1) {
      atomicAdd(&part[(size_t)b * kD + n0],      sum0);
      atomicAdd(&part[(size_t)b * kD + n0 + 16], sum1);
    }
  }
  __syncthreads();
  }  // rep_
}

// ---------- K4: final mean ----------
__global__ __launch_bounds__(128) void k_mean(Raw r, const float* __restrict__ part,
                                              void* __restrict__ out) {
  bool bf = sniff(r);
  int b = blockIdx.x, d = threadIdx.x;
  float v = part[(size_t)b * kD + d] * (1.0f / kC);
  if (bf) ((unsigned short*)out)[b * kD + d] = f2bf(v);
  else    ((float*)out)[b * kD + d] = v;
}

extern "C" void kernel_launch(void* const* d_in, const int* in_sizes, int n_in,
                              void* d_out, int out_size, void* d_ws, size_t ws_size,
                              hipStream_t stream) {
  Raw r;
  r.ops = d_in[0];  r.mask = d_in[1];
  r.rel = (const int*)d_in[2]; r.bidx = (const int*)d_in[3]; r.eidx = (const int*)d_in[4];
  r.ibw = d_in[5];  r.ibb = d_in[6];  r.iew = d_in[7];  r.ieb = d_in[8];
  r.bbw = d_in[9];  r.bbb = d_in[10]; r.bew = d_in[11]; r.beb = d_in[12];
  r.sw  = d_in[13]; r.sb  = d_in[14]; r.aw  = d_in[15]; r.ab  = d_in[16];
  r.scw = d_in[17]; r.scb = d_in[18]; r.aow = d_in[19]; r.aob = d_in[20];
  r.mw  = d_in[21]; r.mb  = d_in[22];

  float* ws    = (float*)d_ws;
  unsigned* feats = (unsigned*)(ws + OF_FEATS);
  unsigned* seq   = (unsigned*)(ws + OF_SEQ);
  unsigned* attnw = (unsigned*)(ws + OF_ATTN);
  float* sq    = ws + OF_SQ;
  float* sk    = ws + OF_SK;
  float* u2    = ws + OF_U;
  float* part  = ws + OF_PART;
  float* bmix  = ws + OF_BMIX;
  unsigned short* wt = (unsigned short*)(ws + OF_WT);
  unsigned short* Vt = (unsigned short*)(ws + OF_V);
  unsigned*     bits = (unsigned*)(ws + OF_V + 1048576);

  k_prep<<<RP_TOT, 256, 0, stream>>>(r, feats, bits, wt, bmix, u2, part);

  for (int l = 0; l < kL; ++l) {
    k_stage1<<<1040, 256, 0, stream>>>(r, l, feats, wt, u2, seq, Vt, sq, sk);
    k_attn_pv_mfma<<<dim3(64, kB), 256, 0, stream>>>(bits, sq, sk, Vt, attnw);
    k_mix64<<<512, 256, 0, stream>>>(r, l, seq, attnw, wt, bmix, feats, d_out, part,
                                     (l == kL - 1) ? 1 : 0);
  }

  k_mean<<<kB, 128, 0, stream>>>(r, part, d_out);
}

// Round 10
// 387.285 us; speedup vs baseline: 1.5084x; 1.5084x over previous
//
#include <hip/hip_runtime.h>

// Problem constants
constexpr int kB = 8;
constexpr int kN = 2046;
constexpr int kC = 2048;   // kN + 2
constexpr int kD = 128;
constexpr int kJ = 128;
constexpr int kL = 2;

typedef short bfrag8 __attribute__((ext_vector_type(8)));
typedef float f32x4 __attribute__((ext_vector_type(4)));

// ---------- bf16 helpers ----------
__device__ __forceinline__ float bf2f(unsigned short h) {
  union { unsigned u; float f; } x; x.u = ((unsigned)h) << 16; return x.f;
}
__device__ __forceinline__ unsigned short f2bf(float f) {
  union { float f; unsigned u; } x; x.f = f;
  unsigned u = x.u;
  if ((u & 0x7fffffffu) > 0x7f800000u) return (unsigned short)((u >> 16) | 0x40);
  return (unsigned short)((u + 0x7fffu + ((u >> 16) & 1u)) >> 16);
}
__device__ __forceinline__ unsigned short f2bf_fast(float f) {  // finite inputs
  union { float f; unsigned u; } x; x.f = f;
  return (unsigned short)((x.u + 0x7fffu + ((x.u >> 16) & 1u)) >> 16);
}
__device__ __forceinline__ void split2(float x, unsigned short& h, unsigned short& l) {
  unsigned short hh = f2bf_fast(x);
  h = hh;
  l = f2bf_fast(x - bf2f(hh));
}
// packed hi/lo bf16 in one u32: lo16 = hi-part, hi16 = lo-part
__device__ __forceinline__ unsigned packhl(float x) {
  unsigned short h, l; split2(x, h, l);
  return (unsigned)h | ((unsigned)l << 16);
}
__device__ __forceinline__ float unpackhl(unsigned u) {
  return bf2f((unsigned short)u) + bf2f((unsigned short)(u >> 16));
}

// ---------- raw input pointers ----------
struct Raw {
  const void *ops, *mask;
  const int *rel, *bidx, *eidx;
  const void *ibw, *ibb, *iew, *ieb;       // init begin/end proj
  const void *bbw, *bbb, *bew, *beb;       // per-layer begin/end proj
  const void *sw, *sb;                     // seq_mix
  const void *aw, *ab;                     // attn_w
  const void *scw, *scb;                   // score
  const void *aow, *aob;                   // attn_out
  const void *mw, *mb;                     // mix
};

__device__ __forceinline__ float rp(const void* p, size_t i, bool bf) {
  return bf ? bf2f(((const unsigned short*)p)[i]) : ((const float*)p)[i];
}

// per-wave dtype sniff over first 1024 words of operation_features
__device__ __forceinline__ bool sniff(const Raw& r) {
  const unsigned* x = (const unsigned*)r.ops;
  int lane = (int)(threadIdx.x & 63);
  int hits = 0;
  #pragma unroll
  for (int q = 0; q < 16; ++q) {
    unsigned w = x[q * 64 + lane];
    unsigned e0 = (w >> 7) & 0xFFu;
    hits += (e0 == 0u || (e0 >= 96u && e0 <= 134u)) ? 1 : 0;
  }
  #pragma unroll
  for (int o = 1; o < 64; o <<= 1) hits += __shfl_xor(hits, o);
  return hits >= 512;
}

// ---------- workspace layout (float offsets) ----------
constexpr size_t OF_FEATS = 0;
constexpr size_t OF_SEQ   = 2097152;
constexpr size_t OF_ATTN  = 4194304;
constexpr size_t OF_V     = 6291456;
constexpr size_t OF_SQ    = 8388608;
constexpr size_t OF_SK    = 8404992;
constexpr size_t OF_U     = 8421376;
constexpr size_t OF_PART  = 8422400;
constexpr size_t OF_BMIX  = 8423424;
constexpr size_t OF_WT    = 8423680;

constexpr int WT_SEQH = 0;
constexpr int WT_SEQL = 49152;
constexpr int WT_VH   = 98304;
constexpr int WT_VL   = 114688;
constexpr int WT_MIXH = 131072;
constexpr int WT_MIXL = 163840;
constexpr int WT_LS   = 196608;

constexpr int RP_WT   = 640;
constexpr int RP_WF   = RP_WT + 258;
constexpr int RP_UV   = RP_WF + 2;
constexpr int RP_BE   = RP_UV + 16;
constexpr int RP_PART = RP_BE + 1;
constexpr int RP_CAST = RP_PART + 1023;
constexpr int RP_TOT  = RP_CAST + 4092;

__device__ __forceinline__ f32x4 mfma16(bfrag8 a, bfrag8 b, f32x4 c) {
  return __builtin_amdgcn_mfma_f32_16x16x32_bf16(a, b, c, 0, 0, 0);
}

// ---------- K0: mega-prep (R8 form) ----------
__global__ __launch_bounds__(256) void k_prep(Raw r, unsigned* __restrict__ feats,
                                              unsigned* __restrict__ bits32,
                                              unsigned short* __restrict__ wt,
                                              float* __restrict__ bmix,
                                              float* __restrict__ u2,
                                              float* __restrict__ part) {
  __shared__ __align__(16) char smem[34816];
  int bid = blockIdx.x, t = threadIdx.x;
  bool bf = sniff(r);

  if (bid < RP_WT) {
    int idx = bid * 256 + t;
    int l = idx / 81920;
    int rr = idx - l * 81920;
    const void* src; size_t si; int dH, dL, k, n;
    if (rr < 49152) {
      k = rr >> 7; n = rr & 127;
      src = r.sw; si = (size_t)l * 49152 + (size_t)k * 128 + n;
      dH = l * WT_LS + WT_SEQH; dL = l * WT_LS + WT_SEQL;
    } else if (rr < 65536) {
      int e = rr - 49152; k = e >> 7; n = e & 127;
      src = r.aw; si = (size_t)l * 49152 + (size_t)k * 384 + 256 + n;
      dH = l * WT_LS + WT_VH; dL = l * WT_LS + WT_VL;
    } else {
      int e = rr - 65536; k = e >> 7; n = e & 127;
      src = r.mw; si = (size_t)l * 32768 + (size_t)k * 128 + n;
      dH = l * WT_LS + WT_MIXH; dL = l * WT_LS + WT_MIXL;
    }
    float v = rp(src, si, bf);
    unsigned short h, lo;
    split2(v, h, lo);
    int kc = k >> 5, q = (k >> 3) & 3, e8 = k & 7;
    int fa = ((kc * 8 + (n >> 4)) * 64 + (q * 16 + (n & 15))) * 8 + e8;
    wt[dH + fa] = h;
    wt[dL + fa] = lo;
  } else if (bid < RP_WF) {
    int rb = bid - RP_WT;
    int l = rb / 129, d1 = rb - l * 129;
    float* vsh = (float*)smem;
    size_t mixbot = (size_t)l * 32768 + 16384;
    if (t < 128) {
      vsh[t] = (d1 < 128) ? rp(r.aow, (size_t)l * 16384 + (size_t)d1 * 128 + t, bf)
                          : rp(r.aob, (size_t)l * 128 + t, bf);
    }
    __syncthreads();
    if (t < 128) {
      int d = t;
      float acc = 0.f;
      if (bf) {
        const unsigned short* mwp = (const unsigned short*)r.mw + mixbot + d;
        #pragma unroll 8
        for (int d2 = 0; d2 < kD; ++d2) acc += vsh[d2] * bf2f(mwp[(size_t)d2 * 128]);
      } else {
        const float* mwp = (const float*)r.mw + mixbot + d;
        #pragma unroll 8
        for (int d2 = 0; d2 < kD; ++d2) acc += vsh[d2] * mwp[(size_t)d2 * 128];
      }
      if (d1 < 128) {
        unsigned short h, lo;
        split2(acc, h, lo);
        int k = 128 + d1;
        int kc = k >> 5, q = (k >> 3) & 3, e8 = k & 7;
        int fa = ((kc * 8 + (d >> 4)) * 64 + (q * 16 + (d & 15))) * 8 + e8;
        wt[l * WT_LS + WT_MIXH + fa] = h;
        wt[l * WT_LS + WT_MIXL + fa] = lo;
      } else {
        bmix[(size_t)l * kD + d] = acc + rp(r.mb, (size_t)l * 128 + d, bf);
      }
    }
  } else if (bid < RP_UV) {
    int l = bid - RP_WF;
    float* swm = (float*)smem;
    float* red = (float*)smem + 256;
    if (t < 128) {
      swm[t]       = rp(r.scw, (size_t)l * 256 + t, bf);
      swm[128 + t] = rp(r.scw, (size_t)l * 256 + 128 + t, bf);
    }
    __syncthreads();
    if (t < 128) {
      int k = t;
      size_t base = (size_t)l * 49152 + (size_t)k * 384;
      float uq = 0.f, uk = 0.f;
      if (bf) {
        const unsigned* aq = (const unsigned*)((const unsigned short*)r.aw + base);
        #pragma unroll 8
        for (int g = 0; g < 64; ++g) {
          unsigned wq = aq[g];
          uq += bf2f((unsigned short)(wq & 0xffffu)) * swm[2 * g]
              + bf2f((unsigned short)(wq >> 16))     * swm[2 * g + 1];
        }
        #pragma unroll 8
        for (int g = 0; g < 64; ++g) {
          unsigned wk = aq[64 + g];
          uk += bf2f((unsigned short)(wk & 0xffffu)) * swm[128 + 2 * g]
              + bf2f((unsigned short)(wk >> 16))     * swm[128 + 2 * g + 1];
        }
      } else {
        const float* aq = (const float*)r.aw + base;
        #pragma unroll 8
        for (int g = 0; g < 32; ++g) {
          float4 v = *(const float4*)(aq + g * 4);
          uq += v.x * swm[4 * g] + v.y * swm[4 * g + 1]
              + v.z * swm[4 * g + 2] + v.w * swm[4 * g + 3];
        }
        #pragma unroll 8
        for (int g = 0; g < 32; ++g) {
          float4 v = *(const float4*)(aq + 128 + g * 4);
          uk += v.x * swm[128 + 4 * g] + v.y * swm[128 + 4 * g + 1]
              + v.z * swm[128 + 4 * g + 2] + v.w * swm[128 + 4 * g + 3];
        }
      }
      float* u = u2 + (size_t)l * 272;
      u[k] = uq; u[128 + k] = uk;
      red[k] = rp(r.ab, (size_t)l * 384 + k, bf) * swm[k]
             + rp(r.ab, (size_t)l * 384 + 128 + k, bf) * swm[128 + k];
    }
    __syncthreads();
    if (t == 0) {
      float s = rp(r.scb, l, bf);
      for (int i = 0; i < 128; ++i) s += red[i];
      u2[(size_t)l * 272 + 256] = s;
    }
  } else if (bid < RP_BE) {
    int rb = bid - RP_UV;
    int b = rb >> 1, sel = rb & 1;
    float* msh = (float*)smem;
    const int* idx = (sel ? r.eidx : r.bidx) + b * kJ;
    const void* wv = sel ? r.iew : r.ibw;
    const void* bb = sel ? r.ieb : r.ibb;
    if (t < 128) {
      int d = t;
      float acc = 0.f;
      if (bf) {
        const unsigned short* op = (const unsigned short*)r.ops;
        #pragma unroll 4
        for (int j = 0; j < kJ; ++j)
          acc += bf2f(op[((size_t)b * kN + idx[j]) * kD + d]);
      } else {
        const float* op = (const float*)r.ops;
        #pragma unroll 4
        for (int j = 0; j < kJ; ++j)
          acc += op[((size_t)b * kN + idx[j]) * kD + d];
      }
      msh[d] = acc * (1.0f / kJ);
    }
    __syncthreads();
    if (t < 128) {
      int d = t;
      float o;
      if (bf) {
        const unsigned short* wp = (const unsigned short*)wv + d;
        o = bf2f(((const unsigned short*)bb)[d]);
        #pragma unroll 8
        for (int k2 = 0; k2 < kD; ++k2) o += msh[k2] * bf2f(wp[(size_t)k2 * kD]);
      } else {
        const float* wp = (const float*)wv + d;
        o = ((const float*)bb)[d];
        #pragma unroll 8
        for (int k2 = 0; k2 < kD; ++k2) o += msh[k2] * wp[(size_t)k2 * kD];
      }
      feats[(size_t)b * kC * kD + (size_t)(kN + sel) * kD + d] = packhl(o);
    }
  } else if (bid < RP_PART) {
    #pragma unroll
    for (int q = 0; q < 4; ++q) part[q * 256 + t] = 0.f;
  } else if (bid < RP_CAST) {
    int idx = (bid - RP_PART) * 256 + t;
    size_t elem = (size_t)idx * 8;
    int b = (int)(elem / (size_t)(kN * kD));
    int rr = (int)(elem - (size_t)b * (kN * kD));
    unsigned* dst = feats + (size_t)b * kC * kD + rr;
    uint4 o0, o1;
    if (bf) {
      uint4 in = ((const uint4*)r.ops)[idx];
      o0.x = in.x & 0xffffu; o0.y = in.x >> 16;
      o0.z = in.y & 0xffffu; o0.w = in.y >> 16;
      o1.x = in.z & 0xffffu; o1.y = in.z >> 16;
      o1.z = in.w & 0xffffu; o1.w = in.w >> 16;
    } else {
      float4 a = ((const float4*)r.ops)[idx * 2];
      float4 c = ((const float4*)r.ops)[idx * 2 + 1];
      o0.x = packhl(a.x); o0.y = packhl(a.y); o0.z = packhl(a.z); o0.w = packhl(a.w);
      o1.x = packhl(c.x); o1.y = packhl(c.y); o1.z = packhl(c.z); o1.w = packhl(c.w);
    }
    *(uint4*)dst = o0;
    *(uint4*)(dst + 4) = o1;
  } else {
    // mask -> bit array via LDS staging
    int wave = t >> 6, lane = t & 63;
    int rr = (bid - RP_CAST) * 4 + wave;
    int b = rr / kN, i = rr - b * kN;
    unsigned* rowbuf = (unsigned*)smem + wave * 2176;
    unsigned word = 0;
    if (bf) {
      const unsigned* g = (const unsigned*)((const char*)r.mask + (size_t)rr * (kN * 2));
      #pragma unroll
      for (int q = 0; q < 16; ++q) {
        int a = q * 64 + lane;
        unsigned v = (a < 1023) ? g[a] : 0u;
        rowbuf[a + (a >> 4)] = v;
      }
      #pragma unroll
      for (int q = 0; q < 16; ++q) {
        int a = lane * 16 + q;
        unsigned v = rowbuf[a + (a >> 4)];
        unsigned b0 = ((v & 0xffffu) != 0u) ? 1u : 0u;
        unsigned b1 = ((v >> 16)     != 0u) ? 1u : 0u;
        word |= (b0 << (2 * q)) | (b1 << (2 * q + 1));
      }
    } else {
      const unsigned* g = (const unsigned*)((const char*)r.mask + (size_t)rr * (kN * 4));
      #pragma unroll
      for (int q = 0; q < 32; ++q) {
        int a = q * 64 + lane;
        unsigned v = (a < 2046) ? g[a] : 0u;
        rowbuf[a + (a >> 4)] = v;
      }
      #pragma unroll
      for (int q = 0; q < 32; ++q) {
        int a = lane * 32 + q;
        unsigned v = rowbuf[a + (a >> 4)];
        union { unsigned u; float f; } x; x.u = v;
        if (x.f != 0.f) word |= (1u << q);
      }
    }
    bits32[((size_t)b * kC + i) * 64 + lane] = word;
  }
}

// ---------- K1: stage1 — 32-row tiles, BK=64 (R8 form) ----------
__global__ __launch_bounds__(256) void k_stage1(Raw r, int l,
    const unsigned* __restrict__ feats, const unsigned short* __restrict__ wt,
    const float* __restrict__ u2, unsigned* __restrict__ seq,
    unsigned short* __restrict__ Vt, float* __restrict__ sq, float* __restrict__ sk)
{
  __shared__ __align__(16) char smem[19712];
  unsigned short (*Ah)[32 * 72] = (unsigned short(*)[32 * 72])smem;
  unsigned short (*Al)[32 * 72] = (unsigned short(*)[32 * 72])(smem + 9216);
  float* su = (float*)(smem + 18432);
  int bid = blockIdx.x, t = threadIdx.x;
  int lane = t & 63, w = t >> 6, m = lane & 15, quad = lane >> 4;
  bool bf = sniff(r);
  const unsigned short* wl = wt + (size_t)l * WT_LS;

  if (bid >= 16) {
    int g = bid - 16;
    bool isv = g >= 512;
    int rb = isv ? g - 512 : g;
    int gr0 = rb * 32;
    int b = gr0 >> 11, r0 = gr0 & 2047;
    int arow = t >> 3, kq = (t & 7) * 8;
    int nl = r0 + arow;
    const unsigned* fb = feats + (size_t)b * kC * kD;
    const unsigned *s0, *s1, *s2;
    if (!isv) {
      int nr = (nl <= kN - 1) ? nl : (kN - 1);
      const int* rel = r.rel + ((size_t)b * kN + nr) * 2;
      int rpd = rel[0], rsc = rel[1];
      int p = (rpd < 0) ? kN : rpd;
      int s = (rsc < 0) ? (kN + 1) : rsc;
      s0 = fb + (size_t)nl * kD;
      s1 = fb + (size_t)p * kD;
      s2 = fb + (size_t)s * kD;
    } else {
      s0 = fb + (size_t)nl * kD; s1 = s0; s2 = s0;
      su[t] = u2[(size_t)l * 272 + t];
    }
    const int K = isv ? 128 : 384;
    const unsigned short* wth = isv ? (wl + WT_VH) : (wl + WT_SEQH);
    const unsigned short* wtl = isv ? (wl + WT_VL) : (wl + WT_SEQL);
    const unsigned short* pbh = wth + (size_t)(w * 2) * 512 + lane * 8;
    const unsigned short* pbl = wtl + (size_t)(w * 2) * 512 + lane * 8;
    float pq = 0.f, pk2 = 0.f;

    auto build = [&](int kb, int buf) {
      int kg = kb + kq;
      const unsigned* sp;
      if (!isv) sp = (kg < 128) ? (s0 + kg) : (kg < 256) ? (s1 + kg - 128) : (s2 + kg - 256);
      else      sp = s0 + kg;
      uint4 U0 = *(const uint4*)sp;
      uint4 U1 = *(const uint4*)(sp + 4);
      if (isv) {
        float f0 = unpackhl(U0.x), f1 = unpackhl(U0.y), f2 = unpackhl(U0.z), f3 = unpackhl(U0.w);
        float f4 = unpackhl(U1.x), f5 = unpackhl(U1.y), f6 = unpackhl(U1.z), f7 = unpackhl(U1.w);
        pq  += f0 * su[kg]     + f1 * su[kg + 1] + f2 * su[kg + 2] + f3 * su[kg + 3]
             + f4 * su[kg + 4] + f5 * su[kg + 5] + f6 * su[kg + 6] + f7 * su[kg + 7];
        pk2 += f0 * su[128 + kg]     + f1 * su[128 + kg + 1] + f2 * su[128 + kg + 2] + f3 * su[128 + kg + 3]
             + f4 * su[128 + kg + 4] + f5 * su[128 + kg + 5] + f6 * su[128 + kg + 6] + f7 * su[128 + kg + 7];
      }
      uint4 ph, pl;
      ph.x = (U0.x & 0xffffu) | (U0.y << 16);
      pl.x = (U0.x >> 16)     | (U0.y & 0xffff0000u);
      ph.y = (U0.z & 0xffffu) | (U0.w << 16);
      pl.y = (U0.z >> 16)     | (U0.w & 0xffff0000u);
      ph.z = (U1.x & 0xffffu) | (U1.y << 16);
      pl.z = (U1.x >> 16)     | (U1.y & 0xffff0000u);
      ph.w = (U1.z & 0xffffu) | (U1.w << 16);
      pl.w = (U1.z >> 16)     | (U1.w & 0xffff0000u);
      *(uint4*)&Ah[buf][arow * 72 + kq] = ph;
      *(uint4*)&Al[buf][arow * 72 + kq] = pl;
    };

    f32x4 acc[2][2];
    #pragma unroll
    for (int mi = 0; mi < 2; ++mi) { acc[mi][0] = {0.f,0.f,0.f,0.f}; acc[mi][1] = {0.f,0.f,0.f,0.f}; }

    __syncthreads();
    build(0, 0);
    __syncthreads();
    for (int kb = 0; kb < K; kb += 64) {
      int cur = (kb >> 6) & 1;
      if (kb + 64 < K) build(kb + 64, cur ^ 1);
      #pragma unroll
      for (int kk = 0; kk < 2; ++kk) {
        int kc = (kb >> 5) + kk;
        bfrag8 bh0 = *(const bfrag8*)(pbh + (size_t)kc * 4096);
        bfrag8 bh1 = *(const bfrag8*)(pbh + (size_t)kc * 4096 + 512);
        bfrag8 bl0 = {}, bl1 = {};
        if (!bf) {
          bl0 = *(const bfrag8*)(pbl + (size_t)kc * 4096);
          bl1 = *(const bfrag8*)(pbl + (size_t)kc * 4096 + 512);
        }
        #pragma unroll
        for (int mi = 0; mi < 2; ++mi) {
          bfrag8 ah = *(const bfrag8*)&Ah[cur][(mi * 16 + m) * 72 + kk * 32 + quad * 8];
          bfrag8 al = *(const bfrag8*)&Al[cur][(mi * 16 + m) * 72 + kk * 32 + quad * 8];
          acc[mi][0] = mfma16(ah, bh0, acc[mi][0]);
          acc[mi][0] = mfma16(al, bh0, acc[mi][0]);
          acc[mi][1] = mfma16(ah, bh1, acc[mi][1]);
          acc[mi][1] = mfma16(al, bh1, acc[mi][1]);
          if (!bf) {
            acc[mi][0] = mfma16(ah, bl0, acc[mi][0]);
            acc[mi][1] = mfma16(ah, bl1, acc[mi][1]);
          }
        }
      }
      __syncthreads();
    }

    int n0 = w * 32 + m;
    if (!isv) {
      float bv0 = rp(r.sb, (size_t)l * 128 + n0, bf);
      float bv1 = rp(r.sb, (size_t)l * 128 + n0 + 16, bf);
      #pragma unroll
      for (int mi = 0; mi < 2; ++mi)
        #pragma unroll
        for (int reg = 0; reg < 4; ++reg) {
          int ra = r0 + mi * 16 + quad * 4 + reg;
          if (ra < kN) {
            seq[((size_t)b * kC + ra) * kD + n0]      = packhl(acc[mi][0][reg] + bv0);
            seq[((size_t)b * kC + ra) * kD + n0 + 16] = packhl(acc[mi][1][reg] + bv1);
          }
        }
    } else {
      float bv0 = rp(r.ab, (size_t)l * 384 + 256 + n0, bf);
      float bv1 = rp(r.ab, (size_t)l * 384 + 256 + n0 + 16, bf);
      unsigned short* vtb = Vt + (size_t)b * 262144;
      #pragma unroll
      for (int mi = 0; mi < 2; ++mi)
        #pragma unroll
        for (int reg = 0; reg < 4; ++reg) {
          int c = r0 + mi * 16 + quad * 4 + reg;
          int kc = c >> 5, cq = (c >> 3) & 3, e8 = c & 7;
          int lp = cq * 16 + m;
          vtb[((kc * 8 + w * 2) * 64 + lp) * 8 + e8]       = f2bf_fast(acc[mi][0][reg] + bv0);
          vtb[((kc * 8 + w * 2 + 1) * 64 + lp) * 8 + e8]   = f2bf_fast(acc[mi][1][reg] + bv1);
        }
      pq  += __shfl_xor(pq, 1);  pq  += __shfl_xor(pq, 2);  pq  += __shfl_xor(pq, 4);
      pk2 += __shfl_xor(pk2, 1); pk2 += __shfl_xor(pk2, 2); pk2 += __shfl_xor(pk2, 4);
      if ((t & 7) == 0) {
        sq[(size_t)b * kC + nl] = pq + u2[(size_t)l * 272 + 256];
        sk[(size_t)b * kC + nl] = pk2;
      }
    }
  } else {
    int rb = bid;
    int b = rb >> 1, sel = rb & 1;
    float* msh = (float*)smem;
    const int* idx = (sel ? r.eidx : r.bidx) + b * kJ;
    const void* wv = sel ? r.bew : r.bbw;
    const void* bb = sel ? r.beb : r.bbb;
    size_t wbase = (size_t)l * kD * kD, bbase = (size_t)l * kD;
    if (t < 128) {
      int d = t;
      const unsigned* fb2 = feats + (size_t)b * kC * kD;
      float acc = 0.f;
      #pragma unroll 4
      for (int j = 0; j < kJ; ++j) acc += unpackhl(fb2[(size_t)idx[j] * kD + d]);
      msh[d] = acc * (1.0f / kJ);
    }
    __syncthreads();
    if (t < 128) {
      int d = t;
      float o;
      if (bf) {
        const unsigned short* wp = (const unsigned short*)wv + wbase + d;
        o = bf2f(((const unsigned short*)bb)[bbase + d]);
        #pragma unroll 8
        for (int k2 = 0; k2 < kD; ++k2) o += msh[k2] * bf2f(wp[(size_t)k2 * kD]);
      } else {
        const float* wp = (const float*)wv + wbase + d;
        o = ((const float*)bb)[bbase + d];
        #pragma unroll 8
        for (int k2 = 0; k2 < kD; ++k2) o += msh[k2] * wp[(size_t)k2 * kD];
      }
      seq[(size_t)b * kC * kD + (size_t)(kN + sel) * kD + d] = packhl(o);
    }
  }
}

// ---------- K2: MFMA PV — padded LDS (conflict-free) + fused zs in PV loop ----------
// sklds padded: float j stored at j + (j>>8)*4  (seg stride 260 -> distinct banks)
// bitlds padded: row stride 68 words            (rows -> distinct banks)
// zs accumulated from the P values buildP computes (removes the whole zs pass)
__global__ __launch_bounds__(256) void k_attn_pv_mfma(
    const unsigned* __restrict__ bits,
    const float* __restrict__ sq, const float* __restrict__ sk,
    const unsigned short* __restrict__ Vt,
    unsigned* __restrict__ outw)
{
  int b = blockIdx.y;
  int i0 = blockIdx.x * 32;
  int t = threadIdx.x, lane = t & 63, w = t >> 6;

  __shared__ unsigned short pshare[2][1024];   // 4 KB
  __shared__ float sklds[2080];                // padded sk row (8.3 KB)
  __shared__ unsigned bitlds[2176];            // 32 rows x 68 words (8.5 KB)
  __shared__ float ssq[32], smx[32], szv[32];
  __shared__ float zred[256];                  // zs partials (1 KB)

  const float* skb = sk + (size_t)b * kC;
  #pragma unroll
  for (int q = 0; q < 8; ++q) {
    int j = q * 256 + t;
    sklds[j + (j >> 8) * 4] = skb[j];
  }
  const unsigned* bitrow = bits + ((size_t)b * kC + i0) * 64;
  #pragma unroll
  for (int q = 0; q < 8; ++q) {
    int g = q * 256 + t;
    bitlds[(g >> 6) * 68 + (g & 63)] = bitrow[g];
  }
  if (t < 32) ssq[t] = sq[(size_t)b * kC + i0 + t];
  __syncthreads();

  {
    // max pass only (zs is fused into the PV loop)
    int rr = t >> 3, seg = t & 7;
    int ig = i0 + rr;
    bool ok = (ig < kN);
    float sqi2 = ssq[rr];
    const unsigned* bw = bitlds + rr * 68 + seg * 8;
    const float* sks = sklds + seg * 260;      // padded segment base
    float mx;
    if (ok) {
      float msk = -3e38f;
      #pragma unroll 1
      for (int w8 = 0; w8 < 8; ++w8) {
        unsigned bb = bw[w8];
        #pragma unroll
        for (int q4 = 0; q4 < 8; ++q4) {
          float4 skv = *(const float4*)(sks + w8 * 32 + q4 * 4);
          unsigned nib = bb >> (q4 * 4);
          msk = (nib & 1u) ? fmaxf(msk, skv.x) : msk;
          msk = (nib & 2u) ? fmaxf(msk, skv.y) : msk;
          msk = (nib & 4u) ? fmaxf(msk, skv.z) : msk;
          msk = (nib & 8u) ? fmaxf(msk, skv.w) : msk;
        }
      }
      #pragma unroll
      for (int d2 = 1; d2 < 8; d2 <<= 1) msk = fmaxf(msk, __shfl_xor(msk, d2));
      float s = sqi2 + msk;
      mx = fmaxf(0.f, fmaxf(s, 0.01f * s));
    } else {
      int j = ig & (kC - 1);
      float s = sqi2 + sklds[j + (j >> 8) * 4];
      mx = fmaxf(0.f, fmaxf(s, 0.01f * s));
    }
    if (seg == 0) smx[rr] = mx;
  }
  __syncthreads();

  int f = t >> 1, h = t & 1;
  int mt_b = f >> 6;
  int lb = f & 63;
  int irow_l = mt_b * 16 + (lb & 15);
  int quad_b = lb >> 4;
  int i_g = i0 + irow_l;
  float sqi = ssq[irow_l];
  float mri = smx[irow_l];
  int joff = quad_b * 8 + h * 4;
  bool irow_ok = (i_g < kN);
  const unsigned char* bitb = (const unsigned char*)(bitlds + irow_l * 68);
  float zsum = 0.f;

  auto buildP = [&](int k0, int buf) {
    float4 skv = *(const float4*)(sklds + k0 + ((k0 >> 8) << 2) + joff);
    unsigned byte;
    if (irow_ok) {
      byte = bitb[(k0 >> 3) + quad_b];
    } else {
      int d0 = i_g - (k0 + quad_b * 8);
      byte = ((unsigned)d0 < 8u) ? (1u << d0) : 0u;
    }
    unsigned nib = byte >> (h * 4);
    unsigned short us[4];
    float sv[4] = {skv.x, skv.y, skv.z, skv.w};
    #pragma unroll
    for (int dj = 0; dj < 4; ++dj) {
      float s = sqi + sv[dj];
      float lr = fmaxf(s, 0.01f * s);
      float val = ((nib >> dj) & 1u) ? lr : 0.f;
      float pv = __expf(val - mri);
      zsum += pv;
      us[dj] = f2bf_fast(pv);
    }
    uint2 pk;
    pk.x = us[0] | ((unsigned)us[1] << 16);
    pk.y = us[2] | ((unsigned)us[3] << 16);
    *(uint2*)(&pshare[buf][f * 8 + h * 4]) = pk;
  };

  f32x4 acc00 = {0.f, 0.f, 0.f, 0.f}, acc01 = acc00, acc10 = acc00, acc11 = acc00;
  int m = lane & 15, quad = lane >> 4;
  int nbase = w * 32;
  const unsigned short* vtb = Vt + (size_t)b * 262144;
  const unsigned short* p0 = vtb + (size_t)(w * 2) * 512 + lane * 8;
  const unsigned short* p1 = p0 + 512;

  buildP(0, 0);
  bfrag8 b0n = *(const bfrag8*)p0;
  bfrag8 b1n = *(const bfrag8*)p1;
  __syncthreads();

  for (int k0 = 0; k0 < kC; k0 += 32) {
    int cur = (k0 >> 5) & 1;
    bfrag8 bf0 = b0n, bf1 = b1n;
    if (k0 + 32 < kC) {
      size_t off = (size_t)((k0 >> 5) + 1) * 4096;
      b0n = *(const bfrag8*)(p0 + off);
      b1n = *(const bfrag8*)(p1 + off);
    }
    bfrag8 a0 = *(const bfrag8*)(&pshare[cur][(0 * 64 + lane) * 8]);
    bfrag8 a1 = *(const bfrag8*)(&pshare[cur][(1 * 64 + lane) * 8]);
    acc00 = mfma16(a0, bf0, acc00);
    acc01 = mfma16(a0, bf1, acc01);
    acc10 = mfma16(a1, bf0, acc10);
    acc11 = mfma16(a1, bf1, acc11);
    if (k0 + 32 < kC) buildP(k0 + 32, cur ^ 1);
    __syncthreads();
  }

  // zs reduction: 8 threads per row -> szv
  zred[t] = zsum;
  __syncthreads();
  if (t < 32) {
    int mt = t >> 4, mm = t & 15;
    float s = 0.f;
    #pragma unroll
    for (int qb = 0; qb < 4; ++qb) {
      int fq = mt * 64 + qb * 16 + mm;
      s += zred[2 * fq] + zred[2 * fq + 1];
    }
    szv[t] = 1.0f / s;
  }
  __syncthreads();

  #pragma unroll
  for (int reg = 0; reg < 4; ++reg) {
    int il_a = quad * 4 + reg;
    int i_a = i0 + il_a;
    int i_b = i_a + 16;
    float za = szv[il_a];
    float zb = szv[il_a + 16];
    unsigned* oa = outw + ((size_t)b * kC + i_a) * kD + nbase + m;
    unsigned* ob = outw + ((size_t)b * kC + i_b) * kD + nbase + m;
    oa[0]  = packhl(acc00[reg] * za);
    oa[16] = packhl(acc01[reg] * za);
    ob[0]  = packhl(acc10[reg] * zb);
    ob[16] = packhl(acc11[reg] * zb);
  }
}

// ---------- K3: mix GEMM — 32-row tiles, BK=64 (R8 form) ----------
__global__ __launch_bounds__(256) void k_mix64(Raw r, int l,
    const unsigned* __restrict__ seqb, const unsigned* __restrict__ attnw,
    const unsigned short* __restrict__ wt, const float* __restrict__ bmix,
    unsigned* __restrict__ featsOut, void* __restrict__ outx, float* __restrict__ part,
    int mode)
{
  __shared__ __align__(16) char smem[18432];
  unsigned short (*Ah)[32 * 72] = (unsigned short(*)[32 * 72])smem;
  unsigned short (*Al)[32 * 72] = (unsigned short(*)[32 * 72])(smem + 9216);
  constexpr int K = 256;
  int bid = blockIdx.x, t = threadIdx.x;
  int lane = t & 63, w = t >> 6, m = lane & 15, quad = lane >> 4;
  bool bf = sniff(r);
  int gr0 = bid * 32;
  int b = gr0 >> 11;
  int arow = t >> 3, kq = (t & 7) * 8;
  const unsigned* s0 = seqb  + (size_t)(gr0 + arow) * kD;
  const unsigned* s1 = attnw + (size_t)(gr0 + arow) * kD;
  const unsigned short* wth = wt + (size_t)l * WT_LS + WT_MIXH;
  const unsigned short* wtl = wt + (size_t)l * WT_LS + WT_MIXL;
  const unsigned short* pbh = wth + (size_t)(w * 2) * 512 + lane * 8;
  const unsigned short* pbl = wtl + (size_t)(w * 2) * 512 + lane * 8;

  auto build = [&](int kb, int buf) {
    int kg = kb + kq;
    const unsigned* sp = (kg < kD) ? (s0 + kg) : (s1 + kg - kD);
    uint4 U0 = *(const uint4*)sp;
    uint4 U1 = *(const uint4*)(sp + 4);
    uint4 ph, pl;
    ph.x = (U0.x & 0xffffu) | (U0.y << 16);
    pl.x = (U0.x >> 16)     | (U0.y & 0xffff0000u);
    ph.y = (U0.z & 0xffffu) | (U0.w << 16);
    pl.y = (U0.z >> 16)     | (U0.w & 0xffff0000u);
    ph.z = (U1.x & 0xffffu) | (U1.y << 16);
    pl.z = (U1.x >> 16)     | (U1.y & 0xffff0000u);
    ph.w = (U1.z & 0xffffu) | (U1.w << 16);
    pl.w = (U1.z >> 16)     | (U1.w & 0xffff0000u);
    *(uint4*)&Ah[buf][arow * 72 + kq] = ph;
    *(uint4*)&Al[buf][arow * 72 + kq] = pl;
  };

  f32x4 acc[2][2];
  #pragma unroll
  for (int mi = 0; mi < 2; ++mi) { acc[mi][0] = {0.f,0.f,0.f,0.f}; acc[mi][1] = {0.f,0.f,0.f,0.f}; }

  build(0, 0);
  __syncthreads();
  for (int kb = 0; kb < K; kb += 64) {
    int cur = (kb >> 6) & 1;
    if (kb + 64 < K) build(kb + 64, cur ^ 1);
    #pragma unroll
    for (int kk = 0; kk < 2; ++kk) {
      int kc = (kb >> 5) + kk;
      bfrag8 bh0 = *(const bfrag8*)(pbh + (size_t)kc * 4096);
      bfrag8 bh1 = *(const bfrag8*)(pbh + (size_t)kc * 4096 + 512);
      bfrag8 bl0 = {}, bl1 = {};
      if (!bf) {
        bl0 = *(const bfrag8*)(pbl + (size_t)kc * 4096);
        bl1 = *(const bfrag8*)(pbl + (size_t)kc * 4096 + 512);
      }
      #pragma unroll
      for (int mi = 0; mi < 2; ++mi) {
        bfrag8 ah = *(const bfrag8*)&Ah[cur][(mi * 16 + m) * 72 + kk * 32 + quad * 8];
        bfrag8 al = *(const bfrag8*)&Al[cur][(mi * 16 + m) * 72 + kk * 32 + quad * 8];
        acc[mi][0] = mfma16(ah, bh0, acc[mi][0]);
        acc[mi][0] = mfma16(al, bh0, acc[mi][0]);
        acc[mi][1] = mfma16(ah, bh1, acc[mi][1]);
        acc[mi][1] = mfma16(al, bh1, acc[mi][1]);
        if (!bf) {
          acc[mi][0] = mfma16(ah, bl0, acc[mi][0]);
          acc[mi][1] = mfma16(ah, bl1, acc[mi][1]);
        }
      }
    }
    __syncthreads();
  }

  int n0 = w * 32 + m;
  float bv0 = bmix[(size_t)l * kD + n0];
  float bv1 = bmix[(size_t)l * kD + n0 + 16];
  if (mode == 0) {
    #pragma unroll
    for (int mi = 0; mi < 2; ++mi)
      #pragma unroll
      for (int reg = 0; reg < 4; ++reg) {
        size_t row = (size_t)gr0 + mi * 16 + quad * 4 + reg;
        featsOut[row * kD + n0]      = packhl(acc[mi][0][reg] + bv0);
        featsOut[row * kD + n0 + 16] = packhl(acc[mi][1][reg] + bv1);
      }
  } else {
    float sum0 = 0.f, sum1 = 0.f;
    #pragma unroll
    for (int mi = 0; mi < 2; ++mi)
      #pragma unroll
      for (int reg = 0; reg < 4; ++reg) {
        size_t row = (size_t)gr0 + mi * 16 + quad * 4 + reg;
        float v0 = acc[mi][0][reg] + bv0;
        float v1 = acc[mi][1][reg] + bv1;
        if (bf) {
          unsigned short* o = (unsigned short*)outx + 1024;
          o[row * kD + n0]      = f2bf(v0);
          o[row * kD + n0 + 16] = f2bf(v1);
        } else {
          float* o = (float*)outx + 1024;
          o[row * kD + n0]      = v0;
          o[row * kD + n0 + 16] = v1;
        }
        sum0 += v0; sum1 += v1;
      }
    sum0 += __shfl_xor(sum0, 16); sum0 += __shfl_xor(sum0, 32);
    sum1 += __shfl_xor(sum1, 16); sum1 += __shfl_xor(sum1, 32);
    if (quad == 0) {
      atomicAdd(&part[(size_t)b * kD + n0],      sum0);
      atomicAdd(&part[(size_t)b * kD + n0 + 16], sum1);
    }
  }
}

// ---------- K4: final mean ----------
__global__ __launch_bounds__(128) void k_mean(Raw r, const float* __restrict__ part,
                                              void* __restrict__ out) {
  bool bf = sniff(r);
  int b = blockIdx.x, d = threadIdx.x;
  float v = part[(size_t)b * kD + d] * (1.0f / kC);
  if (bf) ((unsigned short*)out)[b * kD + d] = f2bf(v);
  else    ((float*)out)[b * kD + d] = v;
}

extern "C" void kernel_launch(void* const* d_in, const int* in_sizes, int n_in,
                              void* d_out, int out_size, void* d_ws, size_t ws_size,
                              hipStream_t stream) {
  Raw r;
  r.ops = d_in[0];  r.mask = d_in[1];
  r.rel = (const int*)d_in[2]; r.bidx = (const int*)d_in[3]; r.eidx = (const int*)d_in[4];
  r.ibw = d_in[5];  r.ibb = d_in[6];  r.iew = d_in[7];  r.ieb = d_in[8];
  r.bbw = d_in[9];  r.bbb = d_in[10]; r.bew = d_in[11]; r.beb = d_in[12];
  r.sw  = d_in[13]; r.sb  = d_in[14]; r.aw  = d_in[15]; r.ab  = d_in[16];
  r.scw = d_in[17]; r.scb = d_in[18]; r.aow = d_in[19]; r.aob = d_in[20];
  r.mw  = d_in[21]; r.mb  = d_in[22];

  float* ws    = (float*)d_ws;
  unsigned* feats = (unsigned*)(ws + OF_FEATS);
  unsigned* seq   = (unsigned*)(ws + OF_SEQ);
  unsigned* attnw = (unsigned*)(ws + OF_ATTN);
  float* sq    = ws + OF_SQ;
  float* sk    = ws + OF_SK;
  float* u2    = ws + OF_U;
  float* part  = ws + OF_PART;
  float* bmix  = ws + OF_BMIX;
  unsigned short* wt = (unsigned short*)(ws + OF_WT);
  unsigned short* Vt = (unsigned short*)(ws + OF_V);
  unsigned*     bits = (unsigned*)(ws + OF_V + 1048576);

  k_prep<<<RP_TOT, 256, 0, stream>>>(r, feats, bits, wt, bmix, u2, part);

  for (int l = 0; l < kL; ++l) {
    k_stage1<<<1040, 256, 0, stream>>>(r, l, feats, wt, u2, seq, Vt, sq, sk);
    k_attn_pv_mfma<<<dim3(64, kB), 256, 0, stream>>>(bits, sq, sk, Vt, attnw);
    k_mix64<<<512, 256, 0, stream>>>(r, l, seq, attnw, wt, bmix, feats, d_out, part,
                                     (l == kL - 1) ? 1 : 0);
  }

  k_mean<<<kB, 128, 0, stream>>>(r, part, d_out);
}